// Round 10
// baseline (517.698 us; speedup 1.0000x reference)
//
#include <hip/hip_runtime.h>
#include <hip/hip_bf16.h>

#define D_DIM 256
#define K_CODES 1024
#define HW 1024
#define N_VEC 32768
#define N_ELEM 8388608ull

typedef __attribute__((ext_vector_type(8))) short bf16x8;
typedef __attribute__((ext_vector_type(4))) float f32x4;
typedef __attribute__((ext_vector_type(2))) float f32x2;

static __device__ __forceinline__ unsigned short f2bf(float x) {
    union { __hip_bfloat16 h; unsigned short u; } cvt;
    cvt.h = __float2bfloat16(x);
    return cvt.u;
}

// ---------------------------------------------------------------------------
// Kernel A (fused prep): codebook -> bf16 B-fragment order + codebook norms
// + zero counts/lossacc. 128 blocks x 256.
// ---------------------------------------------------------------------------
__global__ __launch_bounds__(256) void prep_kernel(const float* __restrict__ cb,
                                                   unsigned short* __restrict__ cbb,
                                                   float* __restrict__ cnorm,
                                                   int* __restrict__ counts,
                                                   float* __restrict__ lossacc) {
    int slot = blockIdx.x * 256 + threadIdx.x;  // 0 .. 32767
    {
        int lane = slot & 63;
        int dchunk = (slot >> 6) & 7;
        int ktile = slot >> 9;
        int code = ktile * 16 + (lane & 15);
        int d0 = dchunk * 32 + (lane >> 4) * 8;
        const float4* src = (const float4*)(cb + (size_t)code * D_DIM + d0);
        float4 v0 = src[0], v1 = src[1];
        int4 o;
        o.x = f2bf(v0.x) | ((unsigned)f2bf(v0.y) << 16);
        o.y = f2bf(v0.z) | ((unsigned)f2bf(v0.w) << 16);
        o.z = f2bf(v1.x) | ((unsigned)f2bf(v1.y) << 16);
        o.w = f2bf(v1.z) | ((unsigned)f2bf(v1.w) << 16);
        *(int4*)(cbb + (size_t)slot * 8) = o;
    }
    if (slot < 8192) {
        if (slot < K_CODES) counts[slot] = 0;
        if (slot == K_CODES) lossacc[0] = 0.f;
        int k = slot >> 3;
        int part = slot & 7;
        const float4* row = (const float4*)(cb + (size_t)k * D_DIM + part * 32);
        float s = 0.f;
#pragma unroll
        for (int i = 0; i < 8; i++) {
            float4 v = row[i];
            s = fmaf(v.x, v.x, s);
            s = fmaf(v.y, v.y, s);
            s = fmaf(v.z, v.z, s);
            s = fmaf(v.w, v.w, s);
        }
        s += __shfl_xor(s, 1);
        s += __shfl_xor(s, 2);
        s += __shfl_xor(s, 4);
        if (part == 0) cnorm[k] = s;
    }
}

// ---------------------------------------------------------------------------
// Kernel B: real fused kernel -- BYTE-IDENTICAL structure to round 9.
// ---------------------------------------------------------------------------
__global__ __launch_bounds__(256, 2) void fused_vq(const float* __restrict__ z,
                                                   const unsigned short* __restrict__ cbb,
                                                   const float* __restrict__ cnorm,
                                                   const float* __restrict__ cb,
                                                   int* __restrict__ indices,
                                                   int* __restrict__ counts,
                                                   float* __restrict__ out,
                                                   float* __restrict__ enc,
                                                   float* __restrict__ lossacc) {
    __shared__ unsigned short Bbuf[4][8192];  // 4 x 16 KB
    __shared__ float cnl[1024];
    __shared__ int bk[64];
    __shared__ float wsum[4];
    const int t = threadIdx.x;
    const int lane = t & 63;
    const int w = t >> 6;
    const int nt0 = blockIdx.x * 4 + w;
    const int row = lane & 15;
    const int dq = (lane >> 4) * 8;
    const int col = lane & 15;
    const int n = nt0 * 16 + row;
    const int b = n >> 10;
    const int hw = n & (HW - 1);

    {
        float4 cv = ((const float4*)cnorm)[t];
        ((float4*)cnl)[t] = cv;
    }
    asm volatile("s_waitcnt lgkmcnt(0)" ::: "memory");

    bf16x8 Ar[8];
#pragma unroll
    for (int dc = 0; dc < 8; dc++) {
        const float* src = z + (((size_t)(b * D_DIM + dc * 32 + dq)) << 10) + hw;
        union { bf16x8 v; unsigned short u[8]; } pk;
#pragma unroll
        for (int j = 0; j < 8; j++) pk.u[j] = f2bf(src[(size_t)j << 10]);
        Ar[dc] = pk.v;
    }

    auto stage = [&](int c) {
        const unsigned int* gsrc = (const unsigned int*)cbb + (size_t)c * 4096;
        unsigned int* l = (unsigned int*)Bbuf[c & 3];
#pragma unroll
        for (int p = 0; p < 4; p++) {
            int off = p * 1024 + t * 4;
            __builtin_amdgcn_global_load_lds(
                (const __attribute__((address_space(1))) unsigned int*)(gsrc + off),
                (__attribute__((address_space(3))) unsigned int*)(l + off), 16, 0, 0);
        }
    };

    float bestd[4];
    int bestk[4];
#pragma unroll
    for (int r = 0; r < 4; r++) { bestd[r] = 3.4e38f; bestk[r] = 0; }

    auto chunk_body = [&](int c) {
        const unsigned short* Bb = Bbuf[c & 3];
        bf16x8 bb[2][8];
#pragma unroll
        for (int kt = 0; kt < 2; kt++)
#pragma unroll
            for (int dc = 0; dc < 8; dc++)
                bb[kt][dc] = *(const bf16x8*)&Bb[((kt * 8 + dc) * 64 + lane) * 8];
        f32x4 acc[2];
#pragma unroll
        for (int kt = 0; kt < 2; kt++) acc[kt] = (f32x4){0.f, 0.f, 0.f, 0.f};
#pragma unroll
        for (int dc = 0; dc < 8; dc++)
#pragma unroll
            for (int kt = 0; kt < 2; kt++)
                acc[kt] = __builtin_amdgcn_mfma_f32_16x16x32_bf16(
                    Ar[dc], bb[kt][dc], acc[kt], 0, 0, 0);
#pragma unroll
        for (int kt = 0; kt < 2; kt++) {
            int k = (c * 2 + kt) * 16 + col;
            float cn = cnl[k];
#pragma unroll
            for (int r = 0; r < 4; r++) {
                float sc = fmaf(-2.0f, acc[kt][r], cn);
                if (sc < bestd[r]) { bestd[r] = sc; bestk[r] = k; }
            }
        }
    };

    stage(0);
    stage(1);
    stage(2);
    for (int c = 0; c < 29; ++c) {
        asm volatile("s_waitcnt vmcnt(8)" ::: "memory");
        __builtin_amdgcn_s_barrier();
        __builtin_amdgcn_sched_barrier(0);
        stage(c + 3);
        chunk_body(c);
    }
    asm volatile("s_waitcnt vmcnt(8)" ::: "memory");
    __builtin_amdgcn_s_barrier();
    __builtin_amdgcn_sched_barrier(0);
    chunk_body(29);
    asm volatile("s_waitcnt vmcnt(4)" ::: "memory");
    __builtin_amdgcn_s_barrier();
    __builtin_amdgcn_sched_barrier(0);
    chunk_body(30);
    asm volatile("s_waitcnt vmcnt(0)" ::: "memory");
    __builtin_amdgcn_s_barrier();
    __builtin_amdgcn_sched_barrier(0);
    chunk_body(31);

#pragma unroll
    for (int r = 0; r < 4; r++) {
        float dd = bestd[r];
        int kk = bestk[r];
#pragma unroll
        for (int off = 8; off >= 1; off >>= 1) {
            float d2 = __shfl_xor(dd, off);
            int k2 = __shfl_xor(kk, off);
            if (d2 < dd || (d2 == dd && k2 < kk)) { dd = d2; kk = k2; }
        }
        if ((lane & 15) == 0) {
            int nloc = w * 16 + (lane >> 4) * 4 + r;
            bk[nloc] = kk;
            indices[blockIdx.x * 64 + nloc] = kk;
            atomicAdd(&counts[kk], 1);
        }
    }
    __syncthreads();

    const int mycode = bk[w * 16 + row];
    const float4* crow4 = (const float4*)(cb + (size_t)mycode * D_DIM);
    float* obase = out + (((size_t)b * D_DIM) << 10) + hw;
    const float* zbase = z + (((size_t)b * D_DIM) << 10) + hw;
    float ls = 0.f;
#pragma unroll
    for (int dc = 0; dc < 8; dc++) {
        const int dbase = dc * 32 + dq;
        float4 qa = crow4[(dbase >> 2) + 0];
        float4 qb = crow4[(dbase >> 2) + 1];
        float qv[8] = {qa.x, qa.y, qa.z, qa.w, qb.x, qb.y, qb.z, qb.w};
#pragma unroll
        for (int j = 0; j < 8; j++) {
            float zv = zbase[(size_t)(dbase + j) << 10];
            float e = qv[j] - zv;
            obase[(size_t)(dbase + j) << 10] = zv + e;
            ls = fmaf(e, e, ls);
        }
    }

    const int n0 = blockIdx.x * 64;
    if (n0 >= 192) {
#pragma unroll 4
        for (int j = 0; j < 64; j++) {
            int idx = bk[j];
            float* rowp = enc + (size_t)(n0 + j) * 1024;
            if (t < 255) {
                int k0 = 2 + t * 4;
                f32x4 v;
                v.x = (k0 == idx) ? 1.f : 0.f;
                v.y = (k0 + 1 == idx) ? 1.f : 0.f;
                v.z = (k0 + 2 == idx) ? 1.f : 0.f;
                v.w = (k0 + 3 == idx) ? 1.f : 0.f;
                __builtin_nontemporal_store(v, (f32x4*)(rowp + k0));
            } else {
                f32x2 hd, tl;
                hd.x = (0 == idx) ? 1.f : 0.f;
                hd.y = (1 == idx) ? 1.f : 0.f;
                tl.x = (1022 == idx) ? 1.f : 0.f;
                tl.y = (1023 == idx) ? 1.f : 0.f;
                __builtin_nontemporal_store(hd, (f32x2*)rowp);
                __builtin_nontemporal_store(tl, (f32x2*)(rowp + 1022));
            }
        }
    }

#pragma unroll
    for (int off = 32; off >= 1; off >>= 1) ls += __shfl_down(ls, off);
    if (lane == 0) wsum[w] = ls;
    __syncthreads();
    if (t == 0) atomicAdd(lossacc, wsum[0] + wsum[1] + wsum[2] + wsum[3]);
}

// ---------------------------------------------------------------------------
// PROBE 1: prologue + 4x the pipelined main loop. NO writes; results kept
// live via asm (rule #17). T ~= Tpro + 4*Tmain. Named so it is identifiable
// in the top-5 table; visible iff > ~100us.
// ---------------------------------------------------------------------------
__global__ __launch_bounds__(256, 2) void probe_main(const float* __restrict__ z,
                                                     const unsigned short* __restrict__ cbb,
                                                     const float* __restrict__ cnorm) {
    __shared__ unsigned short Bbuf[4][8192];
    __shared__ float cnl[1024];
    const int t = threadIdx.x;
    const int lane = t & 63;
    const int w = t >> 6;
    const int nt0 = blockIdx.x * 4 + w;
    const int row = lane & 15;
    const int dq = (lane >> 4) * 8;
    const int col = lane & 15;
    const int n = nt0 * 16 + row;
    const int b = n >> 10;
    const int hw = n & (HW - 1);

    {
        float4 cv = ((const float4*)cnorm)[t];
        ((float4*)cnl)[t] = cv;
    }
    asm volatile("s_waitcnt lgkmcnt(0)" ::: "memory");

    bf16x8 Ar[8];
#pragma unroll
    for (int dc = 0; dc < 8; dc++) {
        const float* src = z + (((size_t)(b * D_DIM + dc * 32 + dq)) << 10) + hw;
        union { bf16x8 v; unsigned short u[8]; } pk;
#pragma unroll
        for (int j = 0; j < 8; j++) pk.u[j] = f2bf(src[(size_t)j << 10]);
        Ar[dc] = pk.v;
    }

    auto stage = [&](int c) {
        const unsigned int* gsrc = (const unsigned int*)cbb + (size_t)c * 4096;
        unsigned int* l = (unsigned int*)Bbuf[c & 3];
#pragma unroll
        for (int p = 0; p < 4; p++) {
            int off = p * 1024 + t * 4;
            __builtin_amdgcn_global_load_lds(
                (const __attribute__((address_space(1))) unsigned int*)(gsrc + off),
                (__attribute__((address_space(3))) unsigned int*)(l + off), 16, 0, 0);
        }
    };

    float bestd[4];
    int bestk[4];
#pragma unroll
    for (int r = 0; r < 4; r++) { bestd[r] = 3.4e38f; bestk[r] = 0; }

    auto chunk_body = [&](int c) {
        const unsigned short* Bb = Bbuf[c & 3];
        bf16x8 bb[2][8];
#pragma unroll
        for (int kt = 0; kt < 2; kt++)
#pragma unroll
            for (int dc = 0; dc < 8; dc++)
                bb[kt][dc] = *(const bf16x8*)&Bb[((kt * 8 + dc) * 64 + lane) * 8];
        f32x4 acc[2];
#pragma unroll
        for (int kt = 0; kt < 2; kt++) acc[kt] = (f32x4){0.f, 0.f, 0.f, 0.f};
#pragma unroll
        for (int dc = 0; dc < 8; dc++)
#pragma unroll
            for (int kt = 0; kt < 2; kt++)
                acc[kt] = __builtin_amdgcn_mfma_f32_16x16x32_bf16(
                    Ar[dc], bb[kt][dc], acc[kt], 0, 0, 0);
#pragma unroll
        for (int kt = 0; kt < 2; kt++) {
            int k = (c * 2 + kt) * 16 + col;
            float cn = cnl[k];
#pragma unroll
            for (int r = 0; r < 4; r++) {
                float sc = fmaf(-2.0f, acc[kt][r], cn);
                if (sc < bestd[r]) { bestd[r] = sc; bestk[r] = k; }
            }
        }
    };

    for (int pass = 0; pass < 4; ++pass) {
        // buffer-reuse safety at restart: last pass's barriers (pre-30, pre-31)
        // guarantee all waves are past chunks 29/30 reads; stage(0/1/2) target
        // bufs 0/1/2 whose last reads were chunks 28/29/30. buf3 (chunk 31,
        // possibly still being read) is untouched; first in-loop barrier fences
        // it before body(0).
        stage(0);
        stage(1);
        stage(2);
        for (int c = 0; c < 29; ++c) {
            asm volatile("s_waitcnt vmcnt(8)" ::: "memory");
            __builtin_amdgcn_s_barrier();
            __builtin_amdgcn_sched_barrier(0);
            stage(c + 3);
            chunk_body(c);
        }
        asm volatile("s_waitcnt vmcnt(8)" ::: "memory");
        __builtin_amdgcn_s_barrier();
        __builtin_amdgcn_sched_barrier(0);
        chunk_body(29);
        asm volatile("s_waitcnt vmcnt(4)" ::: "memory");
        __builtin_amdgcn_s_barrier();
        __builtin_amdgcn_sched_barrier(0);
        chunk_body(30);
        asm volatile("s_waitcnt vmcnt(0)" ::: "memory");
        __builtin_amdgcn_s_barrier();
        __builtin_amdgcn_sched_barrier(0);
        chunk_body(31);
    }

    // keep the whole dataflow live; write NOTHING
#pragma unroll
    for (int r = 0; r < 4; r++)
        asm volatile("" ::"v"(bestd[r]), "v"(bestk[r]));
}

// ---------------------------------------------------------------------------
// PROBE 2: bk from indices (written by fused_vq) + 4x {out/loss epilogue,
// enc epilogue}. All global rewrites idempotent; no atomics (loss kept live
// via asm). T ~= 4*(Tepi1 + Tenc).
// ---------------------------------------------------------------------------
__global__ __launch_bounds__(256, 2) void probe_epi(const float* __restrict__ z,
                                                    const float* __restrict__ cb,
                                                    const int* __restrict__ indices,
                                                    float* __restrict__ out,
                                                    float* __restrict__ enc) {
    __shared__ int bk[64];
    const int t = threadIdx.x;
    const int lane = t & 63;
    const int w = t >> 6;
    const int nt0 = blockIdx.x * 4 + w;
    const int row = lane & 15;
    const int dq = (lane >> 4) * 8;
    const int n = nt0 * 16 + row;
    const int b = n >> 10;
    const int hw = n & (HW - 1);

    if (t < 64) bk[t] = indices[blockIdx.x * 64 + t];
    __syncthreads();

    float ls = 0.f;
    for (int pass = 0; pass < 4; ++pass) {
        const int mycode = bk[w * 16 + row];
        const float4* crow4 = (const float4*)(cb + (size_t)mycode * D_DIM);
        float* obase = out + (((size_t)b * D_DIM) << 10) + hw;
        const float* zbase = z + (((size_t)b * D_DIM) << 10) + hw;
#pragma unroll
        for (int dc = 0; dc < 8; dc++) {
            const int dbase = dc * 32 + dq;
            float4 qa = crow4[(dbase >> 2) + 0];
            float4 qb = crow4[(dbase >> 2) + 1];
            float qv[8] = {qa.x, qa.y, qa.z, qa.w, qb.x, qb.y, qb.z, qb.w};
#pragma unroll
            for (int j = 0; j < 8; j++) {
                float zv = zbase[(size_t)(dbase + j) << 10];
                float e = qv[j] - zv;
                obase[(size_t)(dbase + j) << 10] = zv + e;
                ls = fmaf(e, e, ls);
            }
        }
        const int n0 = blockIdx.x * 64;
        if (n0 >= 192) {
#pragma unroll 4
            for (int j = 0; j < 64; j++) {
                int idx = bk[j];
                float* rowp = enc + (size_t)(n0 + j) * 1024;
                if (t < 255) {
                    int k0 = 2 + t * 4;
                    f32x4 v;
                    v.x = (k0 == idx) ? 1.f : 0.f;
                    v.y = (k0 + 1 == idx) ? 1.f : 0.f;
                    v.z = (k0 + 2 == idx) ? 1.f : 0.f;
                    v.w = (k0 + 3 == idx) ? 1.f : 0.f;
                    __builtin_nontemporal_store(v, (f32x4*)(rowp + k0));
                } else {
                    f32x2 hd, tl;
                    hd.x = (0 == idx) ? 1.f : 0.f;
                    hd.y = (1 == idx) ? 1.f : 0.f;
                    tl.x = (1022 == idx) ? 1.f : 0.f;
                    tl.y = (1023 == idx) ? 1.f : 0.f;
                    __builtin_nontemporal_store(hd, (f32x2*)rowp);
                    __builtin_nontemporal_store(tl, (f32x2*)(rowp + 1022));
                }
            }
        }
    }
    asm volatile("" ::"v"(ls));  // keep loss chain live; no atomic
}

// ---------------------------------------------------------------------------
// Kernel E: finalize loss + perplexity; writes the 192 deferred enc rows.
// ---------------------------------------------------------------------------
__global__ __launch_bounds__(256) void finalize_kernel(const int* __restrict__ counts,
                                                       const float* __restrict__ lossacc,
                                                       const int* __restrict__ indices,
                                                       float* __restrict__ enc,
                                                       float* __restrict__ out_scalars) {
    const int t = threadIdx.x;
    {
        int nrow = blockIdx.x;  // 0..191
        int idx = indices[nrow];
        float* rowp = enc + (size_t)nrow * 1024;
        if (t < 255) {
            int k0 = 2 + t * 4;
            f32x4 v;
            v.x = (k0 == idx) ? 1.f : 0.f;
            v.y = (k0 + 1 == idx) ? 1.f : 0.f;
            v.z = (k0 + 2 == idx) ? 1.f : 0.f;
            v.w = (k0 + 3 == idx) ? 1.f : 0.f;
            __builtin_nontemporal_store(v, (f32x4*)(rowp + k0));
        } else {
            f32x2 hd, tl;
            hd.x = (0 == idx) ? 1.f : 0.f;
            hd.y = (1 == idx) ? 1.f : 0.f;
            tl.x = (1022 == idx) ? 1.f : 0.f;
            tl.y = (1023 == idx) ? 1.f : 0.f;
            __builtin_nontemporal_store(hd, (f32x2*)rowp);
            __builtin_nontemporal_store(tl, (f32x2*)(rowp + 1022));
        }
    }
    if (blockIdx.x != 0) return;
    float s = 0.f;
#pragma unroll
    for (int i = 0; i < 4; i++) {
        int k = t + i * 256;
        float p = (float)counts[k] * (1.0f / 32768.0f);
        s += p * logf(p + 1e-10f);
    }
#pragma unroll
    for (int off = 32; off >= 1; off >>= 1) s += __shfl_down(s, off);
    __shared__ float red[4];
    if ((t & 63) == 0) red[t >> 6] = s;
    __syncthreads();
    if (t == 0) {
        float tot = red[0] + red[1] + red[2] + red[3];
        out_scalars[0] = 1.25f * (lossacc[0] * (1.0f / 8388608.0f));
        out_scalars[1] = expf(-tot);
    }
}

// ---------------------------------------------------------------------------
extern "C" void kernel_launch(void* const* d_in, const int* in_sizes, int n_in,
                              void* d_out, int out_size, void* d_ws, size_t ws_size,
                              hipStream_t stream) {
    const float* z = (const float*)d_in[0];
    const float* cb = (const float*)d_in[1];
    float* out = (float*)d_out;
    char* wsb = (char*)d_ws;

    float* cnorm = (float*)wsb;
    int* counts = (int*)(wsb + 4096);
    float* lossacc = (float*)(wsb + 8192);
    int* indices = (int*)(wsb + 16384);

    float* quant = out;
    float* scal = out + N_ELEM;
    float* enc = out + N_ELEM + 2;
    unsigned short* cbb = (unsigned short*)(out + 8388612);

    hipLaunchKernelGGL(prep_kernel, dim3(128), dim3(256), 0, stream, cb, cbb,
                       cnorm, counts, lossacc);
    hipLaunchKernelGGL(fused_vq, dim3(512), dim3(256), 0, stream, z, cbb,
                       cnorm, cb, indices, counts, quant, enc, lossacc);
    // --- instrumentation probes (idempotent; read real outputs only) ---
    hipLaunchKernelGGL(probe_main, dim3(512), dim3(256), 0, stream, z, cbb, cnorm);
    hipLaunchKernelGGL(probe_epi, dim3(512), dim3(256), 0, stream, z, cb,
                       indices, quant, enc);
    hipLaunchKernelGGL(finalize_kernel, dim3(192), dim3(256), 0, stream, counts,
                       lossacc, indices, enc, scal);
}

// Round 11
// 238.611 us; speedup vs baseline: 2.1696x; 2.1696x over previous
//
#include <hip/hip_runtime.h>
#include <hip/hip_bf16.h>

#define D_DIM 256
#define K_CODES 1024
#define HW 1024
#define N_VEC 32768
#define N_ELEM 8388608ull

typedef __attribute__((ext_vector_type(8))) short bf16x8;
typedef __attribute__((ext_vector_type(4))) float f32x4;
typedef __attribute__((ext_vector_type(2))) float f32x2;

static __device__ __forceinline__ unsigned short f2bf(float x) {
    union { __hip_bfloat16 h; unsigned short u; } cvt;
    cvt.h = __float2bfloat16(x);
    return cvt.u;
}

// ---------------------------------------------------------------------------
// Kernel A (fused prep): codebook -> bf16 B-fragment order + codebook norms
// + zero counts/lossacc. 128 blocks x 256.
// ---------------------------------------------------------------------------
__global__ __launch_bounds__(256) void prep_kernel(const float* __restrict__ cb,
                                                   unsigned short* __restrict__ cbb,
                                                   float* __restrict__ cnorm,
                                                   int* __restrict__ counts,
                                                   float* __restrict__ lossacc) {
    int slot = blockIdx.x * 256 + threadIdx.x;  // 0 .. 32767
    {
        int lane = slot & 63;
        int dchunk = (slot >> 6) & 7;
        int ktile = slot >> 9;
        int code = ktile * 16 + (lane & 15);
        int d0 = dchunk * 32 + (lane >> 4) * 8;
        const float4* src = (const float4*)(cb + (size_t)code * D_DIM + d0);
        float4 v0 = src[0], v1 = src[1];
        int4 o;
        o.x = f2bf(v0.x) | ((unsigned)f2bf(v0.y) << 16);
        o.y = f2bf(v0.z) | ((unsigned)f2bf(v0.w) << 16);
        o.z = f2bf(v1.x) | ((unsigned)f2bf(v1.y) << 16);
        o.w = f2bf(v1.z) | ((unsigned)f2bf(v1.w) << 16);
        *(int4*)(cbb + (size_t)slot * 8) = o;
    }
    if (slot < 8192) {
        if (slot < K_CODES) counts[slot] = 0;
        if (slot == K_CODES) lossacc[0] = 0.f;
        int k = slot >> 3;
        int part = slot & 7;
        const float4* row = (const float4*)(cb + (size_t)k * D_DIM + part * 32);
        float s = 0.f;
#pragma unroll
        for (int i = 0; i < 8; i++) {
            float4 v = row[i];
            s = fmaf(v.x, v.x, s);
            s = fmaf(v.y, v.y, s);
            s = fmaf(v.z, v.z, s);
            s = fmaf(v.w, v.w, s);
        }
        s += __shfl_xor(s, 1);
        s += __shfl_xor(s, 2);
        s += __shfl_xor(s, 4);
        if (part == 0) cnorm[k] = s;
    }
}

// ---------------------------------------------------------------------------
// Kernel B (FUSED): argmin MFMA + STE + loss + one-hot enc.
// R10 ablation: main loop ~19us (done), epilogue ~46us at only 4.1 TB/s --
// the dominant phase. R11 single-variable change vs R9: enc stores are PLAIN
// (through L2), not nontemporal. The harness fill kernel (plain stores)
// sustains 6.5 TB/s on this box; our NT path netted ~4. By epilogue time L2
// holds nothing worth protecting, so bypass buys nothing and costs
// write-combining. Everything else byte-identical to R9 (counted vmcnt(8)
// pipeline, 4x16KB bufs, depth 3, cnorm in LDS, sched_barrier fences).
// cbb aliases enc rows 0..128: blocks 0..2 skip enc; finalize writes 0..191.
// ---------------------------------------------------------------------------
__global__ __launch_bounds__(256, 2) void fused_vq(const float* __restrict__ z,
                                                   const unsigned short* __restrict__ cbb,
                                                   const float* __restrict__ cnorm,
                                                   const float* __restrict__ cb,
                                                   int* __restrict__ indices,
                                                   int* __restrict__ counts,
                                                   float* __restrict__ out,
                                                   float* __restrict__ enc,
                                                   float* __restrict__ lossacc) {
    __shared__ unsigned short Bbuf[4][8192];  // 4 x 16 KB
    __shared__ float cnl[1024];
    __shared__ int bk[64];
    __shared__ float wsum[4];
    const int t = threadIdx.x;
    const int lane = t & 63;
    const int w = t >> 6;
    const int nt0 = blockIdx.x * 4 + w;
    const int row = lane & 15;
    const int dq = (lane >> 4) * 8;
    const int col = lane & 15;
    const int n = nt0 * 16 + row;
    const int b = n >> 10;
    const int hw = n & (HW - 1);

    {
        float4 cv = ((const float4*)cnorm)[t];
        ((float4*)cnl)[t] = cv;
    }
    asm volatile("s_waitcnt lgkmcnt(0)" ::: "memory");

    bf16x8 Ar[8];
#pragma unroll
    for (int dc = 0; dc < 8; dc++) {
        const float* src = z + (((size_t)(b * D_DIM + dc * 32 + dq)) << 10) + hw;
        union { bf16x8 v; unsigned short u[8]; } pk;
#pragma unroll
        for (int j = 0; j < 8; j++) pk.u[j] = f2bf(src[(size_t)j << 10]);
        Ar[dc] = pk.v;
    }

    auto stage = [&](int c) {
        const unsigned int* gsrc = (const unsigned int*)cbb + (size_t)c * 4096;
        unsigned int* l = (unsigned int*)Bbuf[c & 3];
#pragma unroll
        for (int p = 0; p < 4; p++) {
            int off = p * 1024 + t * 4;
            __builtin_amdgcn_global_load_lds(
                (const __attribute__((address_space(1))) unsigned int*)(gsrc + off),
                (__attribute__((address_space(3))) unsigned int*)(l + off), 16, 0, 0);
        }
    };

    float bestd[4];
    int bestk[4];
#pragma unroll
    for (int r = 0; r < 4; r++) { bestd[r] = 3.4e38f; bestk[r] = 0; }

    auto chunk_body = [&](int c) {
        const unsigned short* Bb = Bbuf[c & 3];
        bf16x8 bb[2][8];
#pragma unroll
        for (int kt = 0; kt < 2; kt++)
#pragma unroll
            for (int dc = 0; dc < 8; dc++)
                bb[kt][dc] = *(const bf16x8*)&Bb[((kt * 8 + dc) * 64 + lane) * 8];
        f32x4 acc[2];
#pragma unroll
        for (int kt = 0; kt < 2; kt++) acc[kt] = (f32x4){0.f, 0.f, 0.f, 0.f};
#pragma unroll
        for (int dc = 0; dc < 8; dc++)
#pragma unroll
            for (int kt = 0; kt < 2; kt++)
                acc[kt] = __builtin_amdgcn_mfma_f32_16x16x32_bf16(
                    Ar[dc], bb[kt][dc], acc[kt], 0, 0, 0);
#pragma unroll
        for (int kt = 0; kt < 2; kt++) {
            int k = (c * 2 + kt) * 16 + col;
            float cn = cnl[k];
#pragma unroll
            for (int r = 0; r < 4; r++) {
                float sc = fmaf(-2.0f, acc[kt][r], cn);
                if (sc < bestd[r]) { bestd[r] = sc; bestk[r] = k; }
            }
        }
    };

    stage(0);
    stage(1);
    stage(2);
    for (int c = 0; c < 29; ++c) {
        asm volatile("s_waitcnt vmcnt(8)" ::: "memory");
        __builtin_amdgcn_s_barrier();
        __builtin_amdgcn_sched_barrier(0);
        stage(c + 3);
        chunk_body(c);
    }
    asm volatile("s_waitcnt vmcnt(8)" ::: "memory");
    __builtin_amdgcn_s_barrier();
    __builtin_amdgcn_sched_barrier(0);
    chunk_body(29);
    asm volatile("s_waitcnt vmcnt(4)" ::: "memory");
    __builtin_amdgcn_s_barrier();
    __builtin_amdgcn_sched_barrier(0);
    chunk_body(30);
    asm volatile("s_waitcnt vmcnt(0)" ::: "memory");
    __builtin_amdgcn_s_barrier();
    __builtin_amdgcn_sched_barrier(0);
    chunk_body(31);

#pragma unroll
    for (int r = 0; r < 4; r++) {
        float dd = bestd[r];
        int kk = bestk[r];
#pragma unroll
        for (int off = 8; off >= 1; off >>= 1) {
            float d2 = __shfl_xor(dd, off);
            int k2 = __shfl_xor(kk, off);
            if (d2 < dd || (d2 == dd && k2 < kk)) { dd = d2; kk = k2; }
        }
        if ((lane & 15) == 0) {
            int nloc = w * 16 + (lane >> 4) * 4 + r;
            bk[nloc] = kk;
            indices[blockIdx.x * 64 + nloc] = kk;
            atomicAdd(&counts[kk], 1);
        }
    }
    __syncthreads();

    // ---- epilogue 1: quantize + STE output + loss (z re-read from cache) ----
    const int mycode = bk[w * 16 + row];
    const float4* crow4 = (const float4*)(cb + (size_t)mycode * D_DIM);
    float* obase = out + (((size_t)b * D_DIM) << 10) + hw;
    const float* zbase = z + (((size_t)b * D_DIM) << 10) + hw;
    float ls = 0.f;
#pragma unroll
    for (int dc = 0; dc < 8; dc++) {
        const int dbase = dc * 32 + dq;
        float4 qa = crow4[(dbase >> 2) + 0];
        float4 qb = crow4[(dbase >> 2) + 1];
        float qv[8] = {qa.x, qa.y, qa.z, qa.w, qb.x, qb.y, qb.z, qb.w};
#pragma unroll
        for (int j = 0; j < 8; j++) {
            float zv = zbase[(size_t)(dbase + j) << 10];
            float e = qv[j] - zv;
            obase[(size_t)(dbase + j) << 10] = zv + e;
            ls = fmaf(e, e, ls);
        }
    }

    // ---- epilogue 2: one-hot enc rows, PLAIN stores (through L2) ----
    const int n0 = blockIdx.x * 64;
    if (n0 >= 192) {
#pragma unroll 4
        for (int j = 0; j < 64; j++) {
            int idx = bk[j];
            float* rowp = enc + (size_t)(n0 + j) * 1024;
            if (t < 255) {
                int k0 = 2 + t * 4;
                f32x4 v;
                v.x = (k0 == idx) ? 1.f : 0.f;
                v.y = (k0 + 1 == idx) ? 1.f : 0.f;
                v.z = (k0 + 2 == idx) ? 1.f : 0.f;
                v.w = (k0 + 3 == idx) ? 1.f : 0.f;
                *(f32x4*)(rowp + k0) = v;
            } else {
                f32x2 hd, tl;
                hd.x = (0 == idx) ? 1.f : 0.f;
                hd.y = (1 == idx) ? 1.f : 0.f;
                tl.x = (1022 == idx) ? 1.f : 0.f;
                tl.y = (1023 == idx) ? 1.f : 0.f;
                *(f32x2*)rowp = hd;
                *(f32x2*)(rowp + 1022) = tl;
            }
        }
    }

    // ---- loss reduction ----
#pragma unroll
    for (int off = 32; off >= 1; off >>= 1) ls += __shfl_down(ls, off);
    if (lane == 0) wsum[w] = ls;
    __syncthreads();
    if (t == 0) atomicAdd(lossacc, wsum[0] + wsum[1] + wsum[2] + wsum[3]);
}

// ---------------------------------------------------------------------------
// Kernel E: finalize loss + perplexity; writes the 192 deferred enc rows
// (plain stores, same as fused). 192 blocks.
// ---------------------------------------------------------------------------
__global__ __launch_bounds__(256) void finalize_kernel(const int* __restrict__ counts,
                                                       const float* __restrict__ lossacc,
                                                       const int* __restrict__ indices,
                                                       float* __restrict__ enc,
                                                       float* __restrict__ out_scalars) {
    const int t = threadIdx.x;
    {
        int nrow = blockIdx.x;  // 0..191
        int idx = indices[nrow];
        float* rowp = enc + (size_t)nrow * 1024;
        if (t < 255) {
            int k0 = 2 + t * 4;
            f32x4 v;
            v.x = (k0 == idx) ? 1.f : 0.f;
            v.y = (k0 + 1 == idx) ? 1.f : 0.f;
            v.z = (k0 + 2 == idx) ? 1.f : 0.f;
            v.w = (k0 + 3 == idx) ? 1.f : 0.f;
            *(f32x4*)(rowp + k0) = v;
        } else {
            f32x2 hd, tl;
            hd.x = (0 == idx) ? 1.f : 0.f;
            hd.y = (1 == idx) ? 1.f : 0.f;
            tl.x = (1022 == idx) ? 1.f : 0.f;
            tl.y = (1023 == idx) ? 1.f : 0.f;
            *(f32x2*)rowp = hd;
            *(f32x2*)(rowp + 1022) = tl;
        }
    }
    if (blockIdx.x != 0) return;
    float s = 0.f;
#pragma unroll
    for (int i = 0; i < 4; i++) {
        int k = t + i * 256;
        float p = (float)counts[k] * (1.0f / 32768.0f);
        s += p * logf(p + 1e-10f);
    }
#pragma unroll
    for (int off = 32; off >= 1; off >>= 1) s += __shfl_down(s, off);
    __shared__ float red[4];
    if ((t & 63) == 0) red[t >> 6] = s;
    __syncthreads();
    if (t == 0) {
        float tot = red[0] + red[1] + red[2] + red[3];
        out_scalars[0] = 1.25f * (lossacc[0] * (1.0f / 8388608.0f));
        out_scalars[1] = expf(-tot);
    }
}

// ---------------------------------------------------------------------------
extern "C" void kernel_launch(void* const* d_in, const int* in_sizes, int n_in,
                              void* d_out, int out_size, void* d_ws, size_t ws_size,
                              hipStream_t stream) {
    const float* z = (const float*)d_in[0];
    const float* cb = (const float*)d_in[1];
    float* out = (float*)d_out;
    char* wsb = (char*)d_ws;

    float* cnorm = (float*)wsb;
    int* counts = (int*)(wsb + 4096);
    float* lossacc = (float*)(wsb + 8192);
    int* indices = (int*)(wsb + 16384);

    float* quant = out;
    float* scal = out + N_ELEM;
    float* enc = out + N_ELEM + 2;
    unsigned short* cbb = (unsigned short*)(out + 8388612);

    hipLaunchKernelGGL(prep_kernel, dim3(128), dim3(256), 0, stream, cb, cbb,
                       cnorm, counts, lossacc);
    hipLaunchKernelGGL(fused_vq, dim3(512), dim3(256), 0, stream, z, cbb,
                       cnorm, cb, indices, counts, quant, enc, lossacc);
    hipLaunchKernelGGL(finalize_kernel, dim3(192), dim3(256), 0, stream, counts,
                       lossacc, indices, enc, scal);
}

// Round 12
// 230.900 us; speedup vs baseline: 2.2421x; 1.0334x over previous
//
#include <hip/hip_runtime.h>
#include <hip/hip_bf16.h>

#define D_DIM 256
#define K_CODES 1024
#define HW 1024
#define N_VEC 32768
#define N_ELEM 8388608ull

typedef __attribute__((ext_vector_type(8))) short bf16x8;
typedef __attribute__((ext_vector_type(4))) float f32x4;
typedef __attribute__((ext_vector_type(2))) float f32x2;

static __device__ __forceinline__ unsigned short f2bf(float x) {
    union { __hip_bfloat16 h; unsigned short u; } cvt;
    cvt.h = __float2bfloat16(x);
    return cvt.u;
}

// ---------------------------------------------------------------------------
// Kernel A (fused prep): codebook -> bf16 B-fragment order + codebook norms
// + zero counts/lossacc. 128 blocks x 256.
// ---------------------------------------------------------------------------
__global__ __launch_bounds__(256) void prep_kernel(const float* __restrict__ cb,
                                                   unsigned short* __restrict__ cbb,
                                                   float* __restrict__ cnorm,
                                                   int* __restrict__ counts,
                                                   float* __restrict__ lossacc) {
    int slot = blockIdx.x * 256 + threadIdx.x;  // 0 .. 32767
    {
        int lane = slot & 63;
        int dchunk = (slot >> 6) & 7;
        int ktile = slot >> 9;
        int code = ktile * 16 + (lane & 15);
        int d0 = dchunk * 32 + (lane >> 4) * 8;
        const float4* src = (const float4*)(cb + (size_t)code * D_DIM + d0);
        float4 v0 = src[0], v1 = src[1];
        int4 o;
        o.x = f2bf(v0.x) | ((unsigned)f2bf(v0.y) << 16);
        o.y = f2bf(v0.z) | ((unsigned)f2bf(v0.w) << 16);
        o.z = f2bf(v1.x) | ((unsigned)f2bf(v1.y) << 16);
        o.w = f2bf(v1.z) | ((unsigned)f2bf(v1.w) << 16);
        *(int4*)(cbb + (size_t)slot * 8) = o;
    }
    if (slot < 8192) {
        if (slot < K_CODES) counts[slot] = 0;
        if (slot == K_CODES) lossacc[0] = 0.f;
        int k = slot >> 3;
        int part = slot & 7;
        const float4* row = (const float4*)(cb + (size_t)k * D_DIM + part * 32);
        float s = 0.f;
#pragma unroll
        for (int i = 0; i < 8; i++) {
            float4 v = row[i];
            s = fmaf(v.x, v.x, s);
            s = fmaf(v.y, v.y, s);
            s = fmaf(v.z, v.z, s);
            s = fmaf(v.w, v.w, s);
        }
        s += __shfl_xor(s, 1);
        s += __shfl_xor(s, 2);
        s += __shfl_xor(s, 4);
        if (part == 0) cnorm[k] = s;
    }
}

// ---------------------------------------------------------------------------
// Kernel B (FUSED): argmin MFMA + STE + loss + one-hot enc.
// R11 ledger: pro ~9, main ~19 (floor), epi ~35, seams ~27. R12 changes:
//  (a) stage(0..2) issued BEFORE the z prologue: chunk-0 DMA latency hides
//      under the ~9us z-load latency (the z vmcnt(0) drain covers both).
//  (b) epilogue-1 REMAPPED for full coalescing: since the z re-read (R9),
//      epi1 no longer depends on the MFMA lane mapping. Stage the block's 64
//      winning codebook rows into LDS (qs[64][257] f32, ALIASES the dead
//      Bbuf+cnl region; pad 257 -> (lane+d)%32 = 2-way bank = free), then
//      each wave writes out / reads z in 256B-contiguous runs (wave w owns
//      d = w*64+i, lanes = consecutive hw). Old epi1 wrote 64B quarter-wave
//      segments at 4KB stride.
// Everything else identical to R11 (counted vmcnt(8) pipeline, plain enc
// stores through L2). cbb aliases enc rows 0..128: blocks 0..2 skip enc;
// finalize writes rows 0..191 after (stream order).
// ---------------------------------------------------------------------------
__global__ __launch_bounds__(256, 2) void fused_vq(const float* __restrict__ z,
                                                   const unsigned short* __restrict__ cbb,
                                                   const float* __restrict__ cnorm,
                                                   const float* __restrict__ cb,
                                                   int* __restrict__ indices,
                                                   int* __restrict__ counts,
                                                   float* __restrict__ out,
                                                   float* __restrict__ enc,
                                                   float* __restrict__ lossacc) {
    // union region: [Bbuf 4x16KB ushort | cnl 1024 f32] overlaid by qs[64][257] f32
    __shared__ __align__(16) char smem[69632];
    unsigned short* Bb0 = (unsigned short*)smem;        // 4*8192 ushort
    float* cnl = (float*)(smem + 65536);                // 1024 f32
    float* qs = (float*)smem;                           // [64][257] f32 (epilogue)
    __shared__ int bk[64];
    __shared__ float wsum[4];
    const int t = threadIdx.x;
    const int lane = t & 63;
    const int w = t >> 6;
    const int nt0 = blockIdx.x * 4 + w;
    const int row = lane & 15;
    const int dq = (lane >> 4) * 8;
    const int col = lane & 15;
    const int n = nt0 * 16 + row;
    const int b = n >> 10;
    const int hw = n & (HW - 1);

    // ---- cnorm -> LDS (load consumed immediately; issued before DMAs) ----
    {
        float4 cv = ((const float4*)cnorm)[t];
        ((float4*)cnl)[t] = cv;
    }
    asm volatile("s_waitcnt lgkmcnt(0)" ::: "memory");

    auto stage = [&](int c) {
        const unsigned int* gsrc = (const unsigned int*)cbb + (size_t)c * 4096;
        unsigned int* l = (unsigned int*)(Bb0 + (size_t)(c & 3) * 8192);
#pragma unroll
        for (int p = 0; p < 4; p++) {
            int off = p * 1024 + t * 4;
            __builtin_amdgcn_global_load_lds(
                (const __attribute__((address_space(1))) unsigned int*)(gsrc + off),
                (__attribute__((address_space(3))) unsigned int*)(l + off), 16, 0, 0);
        }
    };

    // ---- (a) early DMA issue: chunks 0..2 in flight during the z prologue ----
    stage(0);
    stage(1);
    stage(2);

    // ---- prologue: z -> bf16 A fragments ----
    bf16x8 Ar[8];
#pragma unroll
    for (int dc = 0; dc < 8; dc++) {
        const float* src = z + (((size_t)(b * D_DIM + dc * 32 + dq)) << 10) + hw;
        union { bf16x8 v; unsigned short u[8]; } pk;
#pragma unroll
        for (int j = 0; j < 8; j++) pk.u[j] = f2bf(src[(size_t)j << 10]);
        Ar[dc] = pk.v;
    }

    float bestd[4];
    int bestk[4];
#pragma unroll
    for (int r = 0; r < 4; r++) { bestd[r] = 3.4e38f; bestk[r] = 0; }

    auto chunk_body = [&](int c) {
        const unsigned short* Bb = Bb0 + (size_t)(c & 3) * 8192;
        bf16x8 bb[2][8];
#pragma unroll
        for (int kt = 0; kt < 2; kt++)
#pragma unroll
            for (int dc = 0; dc < 8; dc++)
                bb[kt][dc] = *(const bf16x8*)&Bb[((kt * 8 + dc) * 64 + lane) * 8];
        f32x4 acc[2];
#pragma unroll
        for (int kt = 0; kt < 2; kt++) acc[kt] = (f32x4){0.f, 0.f, 0.f, 0.f};
#pragma unroll
        for (int dc = 0; dc < 8; dc++)
#pragma unroll
            for (int kt = 0; kt < 2; kt++)
                acc[kt] = __builtin_amdgcn_mfma_f32_16x16x32_bf16(
                    Ar[dc], bb[kt][dc], acc[kt], 0, 0, 0);
#pragma unroll
        for (int kt = 0; kt < 2; kt++) {
            int k = (c * 2 + kt) * 16 + col;
            float cn = cnl[k];
#pragma unroll
            for (int r = 0; r < 4; r++) {
                float sc = fmaf(-2.0f, acc[kt][r], cn);
                if (sc < bestd[r]) { bestd[r] = sc; bestk[r] = k; }
            }
        }
    };

    for (int c = 0; c < 29; ++c) {
        asm volatile("s_waitcnt vmcnt(8)" ::: "memory");
        __builtin_amdgcn_s_barrier();
        __builtin_amdgcn_sched_barrier(0);
        stage(c + 3);
        chunk_body(c);
    }
    asm volatile("s_waitcnt vmcnt(8)" ::: "memory");
    __builtin_amdgcn_s_barrier();
    __builtin_amdgcn_sched_barrier(0);
    chunk_body(29);
    asm volatile("s_waitcnt vmcnt(4)" ::: "memory");
    __builtin_amdgcn_s_barrier();
    __builtin_amdgcn_sched_barrier(0);
    chunk_body(30);
    asm volatile("s_waitcnt vmcnt(0)" ::: "memory");
    __builtin_amdgcn_s_barrier();
    __builtin_amdgcn_sched_barrier(0);
    chunk_body(31);

    // ---- reduce across the 16 columns; stash winning codes in LDS ----
#pragma unroll
    for (int r = 0; r < 4; r++) {
        float dd = bestd[r];
        int kk = bestk[r];
#pragma unroll
        for (int off = 8; off >= 1; off >>= 1) {
            float d2 = __shfl_xor(dd, off);
            int k2 = __shfl_xor(kk, off);
            if (d2 < dd || (d2 == dd && k2 < kk)) { dd = d2; kk = k2; }
        }
        if ((lane & 15) == 0) {
            int nloc = w * 16 + (lane >> 4) * 4 + r;
            bk[nloc] = kk;
            indices[blockIdx.x * 64 + nloc] = kk;
            atomicAdd(&counts[kk], 1);
        }
    }
    __syncthreads();  // bk ready; all Bbuf/cnl reads done -> qs may overwrite

    // ---- epilogue 1a: stage 64 winning codebook rows into LDS (qs) ----
    {
        const int j = t >> 2;    // row 0..63
        const int part = t & 3;  // 4 threads per row
        const float4* src = (const float4*)(cb + (size_t)bk[j] * D_DIM);
        float* dst = qs + (size_t)j * 257;
#pragma unroll
        for (int i = 0; i < 16; i++) {
            int f4 = part + 4 * i;  // 0..63
            float4 v = src[f4];
            dst[f4 * 4 + 0] = v.x;
            dst[f4 * 4 + 1] = v.y;
            dst[f4 * 4 + 2] = v.z;
            dst[f4 * 4 + 3] = v.w;
        }
    }
    __syncthreads();

    // ---- epilogue 1b: coalesced quantize + STE + loss ----
    // wave w owns d = w*64 + i; lanes = consecutive hw -> 256B contiguous.
    const int hw0 = (blockIdx.x * 64) & (HW - 1);
    const int bb2 = (blockIdx.x * 64) >> 10;
    float ls = 0.f;
#pragma unroll 8
    for (int i = 0; i < 64; i++) {
        int d = w * 64 + i;
        size_t o = (((size_t)(bb2 * D_DIM + d)) << 10) + hw0 + lane;
        float q = qs[(size_t)lane * 257 + d];
        float zv = z[o];
        float e = q - zv;
        out[o] = zv + e;
        ls = fmaf(e, e, ls);
    }

    // ---- epilogue 2: one-hot enc rows, plain stores through L2 ----
    const int n0 = blockIdx.x * 64;
    if (n0 >= 192) {
#pragma unroll 4
        for (int j = 0; j < 64; j++) {
            int idx = bk[j];
            float* rowp = enc + (size_t)(n0 + j) * 1024;
            if (t < 255) {
                int k0 = 2 + t * 4;
                f32x4 v;
                v.x = (k0 == idx) ? 1.f : 0.f;
                v.y = (k0 + 1 == idx) ? 1.f : 0.f;
                v.z = (k0 + 2 == idx) ? 1.f : 0.f;
                v.w = (k0 + 3 == idx) ? 1.f : 0.f;
                *(f32x4*)(rowp + k0) = v;
            } else {
                f32x2 hd, tl;
                hd.x = (0 == idx) ? 1.f : 0.f;
                hd.y = (1 == idx) ? 1.f : 0.f;
                tl.x = (1022 == idx) ? 1.f : 0.f;
                tl.y = (1023 == idx) ? 1.f : 0.f;
                *(f32x2*)rowp = hd;
                *(f32x2*)(rowp + 1022) = tl;
            }
        }
    }

    // ---- loss reduction ----
#pragma unroll
    for (int off = 32; off >= 1; off >>= 1) ls += __shfl_down(ls, off);
    if (lane == 0) wsum[w] = ls;
    __syncthreads();
    if (t == 0) atomicAdd(lossacc, wsum[0] + wsum[1] + wsum[2] + wsum[3]);
}

// ---------------------------------------------------------------------------
// Kernel E: finalize loss + perplexity; writes the 192 deferred enc rows
// (plain stores). 192 blocks.
// ---------------------------------------------------------------------------
__global__ __launch_bounds__(256) void finalize_kernel(const int* __restrict__ counts,
                                                       const float* __restrict__ lossacc,
                                                       const int* __restrict__ indices,
                                                       float* __restrict__ enc,
                                                       float* __restrict__ out_scalars) {
    const int t = threadIdx.x;
    {
        int nrow = blockIdx.x;  // 0..191
        int idx = indices[nrow];
        float* rowp = enc + (size_t)nrow * 1024;
        if (t < 255) {
            int k0 = 2 + t * 4;
            f32x4 v;
            v.x = (k0 == idx) ? 1.f : 0.f;
            v.y = (k0 + 1 == idx) ? 1.f : 0.f;
            v.z = (k0 + 2 == idx) ? 1.f : 0.f;
            v.w = (k0 + 3 == idx) ? 1.f : 0.f;
            *(f32x4*)(rowp + k0) = v;
        } else {
            f32x2 hd, tl;
            hd.x = (0 == idx) ? 1.f : 0.f;
            hd.y = (1 == idx) ? 1.f : 0.f;
            tl.x = (1022 == idx) ? 1.f : 0.f;
            tl.y = (1023 == idx) ? 1.f : 0.f;
            *(f32x2*)rowp = hd;
            *(f32x2*)(rowp + 1022) = tl;
        }
    }
    if (blockIdx.x != 0) return;
    float s = 0.f;
#pragma unroll
    for (int i = 0; i < 4; i++) {
        int k = t + i * 256;
        float p = (float)counts[k] * (1.0f / 32768.0f);
        s += p * logf(p + 1e-10f);
    }
#pragma unroll
    for (int off = 32; off >= 1; off >>= 1) s += __shfl_down(s, off);
    __shared__ float red[4];
    if ((t & 63) == 0) red[t >> 6] = s;
    __syncthreads();
    if (t == 0) {
        float tot = red[0] + red[1] + red[2] + red[3];
        out_scalars[0] = 1.25f * (lossacc[0] * (1.0f / 8388608.0f));
        out_scalars[1] = expf(-tot);
    }
}

// ---------------------------------------------------------------------------
extern "C" void kernel_launch(void* const* d_in, const int* in_sizes, int n_in,
                              void* d_out, int out_size, void* d_ws, size_t ws_size,
                              hipStream_t stream) {
    const float* z = (const float*)d_in[0];
    const float* cb = (const float*)d_in[1];
    float* out = (float*)d_out;
    char* wsb = (char*)d_ws;

    float* cnorm = (float*)wsb;
    int* counts = (int*)(wsb + 4096);
    float* lossacc = (float*)(wsb + 8192);
    int* indices = (int*)(wsb + 16384);

    float* quant = out;
    float* scal = out + N_ELEM;
    float* enc = out + N_ELEM + 2;
    unsigned short* cbb = (unsigned short*)(out + 8388612);

    hipLaunchKernelGGL(prep_kernel, dim3(128), dim3(256), 0, stream, cb, cbb,
                       cnorm, counts, lossacc);
    hipLaunchKernelGGL(fused_vq, dim3(512), dim3(256), 0, stream, z, cbb,
                       cnorm, cb, indices, counts, quant, enc, lossacc);
    hipLaunchKernelGGL(finalize_kernel, dim3(192), dim3(256), 0, stream, counts,
                       lossacc, indices, enc, scal);
}